// Round 6
// baseline (215.264 us; speedup 1.0000x reference)
//
#include <hip/hip_runtime.h>
#include <hip/hip_bf16.h>
#include <math.h>

#define Bt 8
#define Ct 64
#define Ht 128
#define Wt 128
#define Ot 64
#define HWt (Ht*Wt)

typedef __bf16 bf16x8 __attribute__((ext_vector_type(8)));
typedef float  f32x4  __attribute__((ext_vector_type(4)));

// fp32 -> bf16 bits, round-to-nearest-even, integer ops only
__device__ __forceinline__ uint f2bf_bits(float v) {
    uint u = __float_as_uint(v);
    uint lsb = (u >> 16) & 1u;
    return (u + 0x7fffu + lsb) >> 16;
}
__device__ __forceinline__ ushort f2bf(float v) {
    return (ushort)f2bf_bits(v);
}

// ---------------- prep ----------------
// blocks 0..1023: transpose x NCHW fp32 -> xTb NHWC bf16  [b][y][x][c]
// blocks 1024.. : weight reshapes
//   wOffB[(k*32+ch)*64+c] = ch<18 ? w_off[ch][c][k] : ch<27 ? w_mask[ch-18][c][k] : 0
//   wMainB[(k*64+o)*64+c] = w_dcn[o][c][k]
__global__ __launch_bounds__(256) void prep_kernel(
    const float* __restrict__ x, const float* __restrict__ w_off,
    const float* __restrict__ w_mask, const float* __restrict__ w_dcn,
    ushort* __restrict__ xTb, ushort* __restrict__ wOffB, ushort* __restrict__ wMainB)
{
    int blk = blockIdx.x;
    int t = threadIdx.x;
    if (blk < 1024) {
        __shared__ float L[64][128];
        int b = blk >> 7, y = blk & 127;
        const float* xb = x + (size_t)b * 1048576 + y * 128;
        int xx = t & 127, ch2 = t >> 7;
#pragma unroll
        for (int cc = 0; cc < 32; ++cc) {
            int c = cc * 2 + ch2;
            L[c][xx] = xb[(size_t)c * HWt + xx];
        }
        __syncthreads();
        int px = t >> 1, half = (t & 1) * 32;
        union { ushort u[32]; uint4 q[4]; } pk;
#pragma unroll
        for (int i = 0; i < 32; ++i) pk.u[i] = f2bf(L[half + i][px]);
        uint4* dst = (uint4*)(xTb + ((size_t)blk * 128 + px) * 64 + half);
        dst[0] = pk.q[0]; dst[1] = pk.q[1]; dst[2] = pk.q[2]; dst[3] = pk.q[3];
    } else {
        int i = (blk - 1024) * 256 + t;
        if (i < 9 * 32 * 64) {
            int c = i & 63, ch = (i >> 6) & 31, k = i >> 11;
            float v = 0.f;
            if (ch < 18)      v = w_off[(ch * 64 + c) * 9 + k];
            else if (ch < 27) v = w_mask[((ch - 18) * 64 + c) * 9 + k];
            wOffB[i] = f2bf(v);
        } else {
            int j = i - 18432;
            if (j < 9 * 64 * 64) {
                int c = j & 63, o = (j >> 6) & 63, k = j >> 12;
                wMainB[j] = f2bf(w_dcn[(o * 64 + c) * 9 + k]);
            }
        }
    }
}

// ---------------- fused: offset conv + bilinear sample + MFMA ----------------
// block: 64 px, 4 waves x M=16; phase A: N=32 offset conv (B from global,
// barrier-free); phase B: N=64 main contraction (B staged in LDS 3-tap groups).
// Offsets never touch HBM: phase A -> off3[] LDS -> phase B registers.
__global__ __launch_bounds__(256) void dcn_fused_kernel(
    const ushort* __restrict__ xTb, const ushort* __restrict__ wOffB,
    const ushort* __restrict__ wMainB,
    const float* __restrict__ b_off, const float* __restrict__ b_mask,
    const float* __restrict__ b_dcn, float* __restrict__ out)
{
    __shared__ ushort wS[192 * 72];   // 27 KB, main weights (3-tap groups)
    __shared__ float off3[27][65];    // 6.86 KB: rows 0-8 dy, 9-17 dx, 18-26 mask

    int t = threadIdx.x;
    int p0 = blockIdx.x * 64;
    int b = p0 >> 14, rem = p0 & 16383, y = rem >> 7, x0 = rem & 127;
    int wv = t >> 6, ln = t & 63;
    int m = ln & 15, cq = ln >> 4;
    int px = wv * 16 + m;
    const ushort* xbb = xTb + (size_t)b * 1048576;

    // stage phase-B group-0 weights EARLY (independent of phase A)
#pragma unroll
    for (int it = 0; it < 6; ++it) {
        int j = it * 256 + t;
        int row = j >> 3, ch8 = j & 7;
        *(uint4*)&wS[row * 72 + ch8 * 8] =
            *(const uint4*)&wMainB[(size_t)row * 64 + ch8 * 8];
    }

    // ---- Phase A: offset/mask conv, fully unrolled, barrier-free ----
    {
        f32x4 acc0 = {0.f, 0.f, 0.f, 0.f};
        f32x4 acc1 = {0.f, 0.f, 0.f, 0.f};
        int gx = x0 + px;
#pragma unroll
        for (int k = 0; k < 9; ++k) {
            int ky = k / 3, kx = k - ky * 3;
            int yy = y + ky - 1;
            int xx = gx + kx - 1;
            bool ok = ((unsigned)yy < 128u) && ((unsigned)xx < 128u);
            const ushort* arow = xbb + ((size_t)((yy << 7) + xx)) * 64;
            const ushort* wk = wOffB + (size_t)k * 2048;
#pragma unroll
            for (int ks = 0; ks < 2; ++ks) {
                int c0 = ks * 32 + cq * 8;
                uint4 av = {0u, 0u, 0u, 0u};
                if (ok) av = *(const uint4*)&arow[c0];
                bf16x8 a  = __builtin_bit_cast(bf16x8, av);
                bf16x8 b0 = __builtin_bit_cast(bf16x8, *(const uint4*)&wk[m * 64 + c0]);
                bf16x8 b1 = __builtin_bit_cast(bf16x8, *(const uint4*)&wk[(16 + m) * 64 + c0]);
                acc0 = __builtin_amdgcn_mfma_f32_16x16x32_bf16(a, b0, acc0, 0, 0, 0);
                acc1 = __builtin_amdgcn_mfma_f32_16x16x32_bf16(a, b1, acc1, 0, 0, 0);
            }
        }
        // epilogue A: C layout col=ch (lane&15), row=px (wv*16+(ln>>4)*4+r)
        int pxl = wv * 16 + (cq << 2);
#pragma unroll
        for (int r = 0; r < 4; ++r) {
            int pp = pxl + r;
            int ch0 = m;                                   // 0..15
            off3[(ch0 & 1) * 9 + (ch0 >> 1)][pp] = acc0[r] + b_off[ch0];
            int ch1 = 16 + m;                              // 16..31
            if (ch1 < 18) {
                off3[(ch1 & 1) * 9 + (ch1 >> 1)][pp] = acc1[r] + b_off[ch1];
            } else if (ch1 < 27) {
                float v = acc1[r] + b_mask[ch1 - 18];
                off3[ch1][pp] = 1.f / (1.f + __expf(-v));
            }
        }
    }
    __syncthreads();   // off3 ready AND wS group-0 ready

    // preload this lane's 27 offset/mask values into registers
    float odm[3][9];
#pragma unroll
    for (int k = 0; k < 9; ++k) {
        odm[0][k] = off3[k][px];
        odm[1][k] = off3[9 + k][px];
        odm[2][k] = off3[18 + k][px];
    }

    // ---- Phase B: bilinear sample + main contraction ----
    f32x4 acc[4];
#pragma unroll
    for (int i = 0; i < 4; ++i) acc[i] = f32x4{0.f, 0.f, 0.f, 0.f};
    float fx = (float)(x0 + px);

#pragma unroll
    for (int g = 0; g < 3; ++g) {
        if (g > 0) {
            __syncthreads();   // protect previous group's reads
#pragma unroll
            for (int it = 0; it < 6; ++it) {
                int j = it * 256 + t;
                int row = j >> 3, ch8 = j & 7;
                *(uint4*)&wS[row * 72 + ch8 * 8] =
                    *(const uint4*)&wMainB[(size_t)(g * 192 + row) * 64 + ch8 * 8];
            }
            __syncthreads();
        }

#pragma unroll
        for (int tl = 0; tl < 3; ++tl) {
            int k = g * 3 + tl;
            int ky = k / 3, kx = k - ky * 3;
            float dyv = odm[0][k];
            float dxv = odm[1][k];
            float mkv = odm[2][k];
            float py  = (float)(y + ky - 1) + dyv;
            float pxf = fx + (float)(kx - 1) + dxv;
            float y0f = floorf(py), x0f = floorf(pxf);
            float wy1 = py - y0f, wy0 = 1.f - wy1;
            float wx1 = pxf - x0f, wx0 = 1.f - wx1;
            bool vy0 = (y0f >= 0.f) && (y0f <= 127.f);
            bool vy1 = (y0f >= -1.f) && (y0f <= 126.f);
            bool vx0 = (x0f >= 0.f) && (x0f <= 127.f);
            bool vx1 = (x0f >= -1.f) && (x0f <= 126.f);
            float w00 = (vy0 && vx0) ? wy0 * wx0 * mkv : 0.f;
            float w01 = (vy0 && vx1) ? wy0 * wx1 * mkv : 0.f;
            float w10 = (vy1 && vx0) ? wy1 * wx0 * mkv : 0.f;
            float w11 = (vy1 && vx1) ? wy1 * wx1 * mkv : 0.f;
            int yi0 = (int)y0f, xi0 = (int)x0f;
            int y0c = min(max(yi0, 0), 127),     y1c = min(max(yi0 + 1, 0), 127);
            int x0c = min(max(xi0, 0), 127),     x1c = min(max(xi0 + 1, 0), 127);
            const ushort* p00 = xbb + (size_t)((y0c << 7) + x0c) * 64;
            const ushort* p01 = xbb + (size_t)((y0c << 7) + x1c) * 64;
            const ushort* p10 = xbb + (size_t)((y1c << 7) + x0c) * 64;
            const ushort* p11 = xbb + (size_t)((y1c << 7) + x1c) * 64;

            bf16x8 afr[2];
#pragma unroll
            for (int ks = 0; ks < 2; ++ks) {
                int c0 = ks * 32 + cq * 8;
                union { uint4 q; uint u[4]; } v00, v01, v10, v11, wr;
                v00.q = *(const uint4*)(p00 + c0);
                v01.q = *(const uint4*)(p01 + c0);
                v10.q = *(const uint4*)(p10 + c0);
                v11.q = *(const uint4*)(p11 + c0);
#pragma unroll
                for (int j = 0; j < 4; ++j) {
                    float f00l = __uint_as_float(v00.u[j] << 16);
                    float f00h = __uint_as_float(v00.u[j] & 0xffff0000u);
                    float f01l = __uint_as_float(v01.u[j] << 16);
                    float f01h = __uint_as_float(v01.u[j] & 0xffff0000u);
                    float f10l = __uint_as_float(v10.u[j] << 16);
                    float f10h = __uint_as_float(v10.u[j] & 0xffff0000u);
                    float f11l = __uint_as_float(v11.u[j] << 16);
                    float f11h = __uint_as_float(v11.u[j] & 0xffff0000u);
                    float vl = w00 * f00l;
                    vl = fmaf(w01, f01l, vl); vl = fmaf(w10, f10l, vl); vl = fmaf(w11, f11l, vl);
                    float vh = w00 * f00h;
                    vh = fmaf(w01, f01h, vh); vh = fmaf(w10, f10h, vh); vh = fmaf(w11, f11h, vh);
                    wr.u[j] = (f2bf_bits(vh) << 16) | f2bf_bits(vl);
                }
                afr[ks] = __builtin_bit_cast(bf16x8, wr.q);
            }

#pragma unroll
            for (int ks = 0; ks < 2; ++ks) {
                int c0 = ks * 32 + cq * 8;
#pragma unroll
                for (int nt = 0; nt < 4; ++nt) {
                    bf16x8 bb = __builtin_bit_cast(bf16x8,
                        *(const uint4*)&wS[(tl * 64 + nt * 16 + m) * 72 + c0]);
                    acc[nt] = __builtin_amdgcn_mfma_f32_16x16x32_bf16(afr[ks], bb, acc[nt], 0, 0, 0);
                }
            }
        }
    }

    // epilogue: direct coalesced float4 stores from C layout
#pragma unroll
    for (int nt = 0; nt < 4; ++nt) {
        int o = nt * 16 + m;
        float bias = b_dcn[o];
        float4 v;
        v.x = acc[nt][0] + bias;
        v.y = acc[nt][1] + bias;
        v.z = acc[nt][2] + bias;
        v.w = acc[nt][3] + bias;
        float* orow = out + ((size_t)(b * 64 + o) << 14) + (y << 7) + x0 + wv * 16 + cq * 4;
        *(float4*)orow = v;
    }
}

extern "C" void kernel_launch(void* const* d_in, const int* in_sizes, int n_in,
                              void* d_out, int out_size, void* d_ws, size_t ws_size,
                              hipStream_t stream) {
    const float* x      = (const float*)d_in[0];
    const float* w_off  = (const float*)d_in[1];
    const float* b_off  = (const float*)d_in[2];
    const float* w_mask = (const float*)d_in[3];
    const float* b_mask = (const float*)d_in[4];
    const float* w_dcn  = (const float*)d_in[5];
    const float* b_dcn  = (const float*)d_in[6];
    float* out = (float*)d_out;

    ushort* xTb    = (ushort*)d_ws;                  // 8.4M bf16
    ushort* wOffB  = xTb + (size_t)Bt * HWt * 64;    // 18432
    ushort* wMainB = wOffB + 18432;                  // 36864

    hipLaunchKernelGGL(prep_kernel, dim3(1024 + 216), dim3(256), 0, stream,
                       x, w_off, w_mask, w_dcn, xTb, wOffB, wMainB);
    hipLaunchKernelGGL(dcn_fused_kernel, dim3(2048), dim3(256), 0, stream,
                       xTb, wOffB, wMainB, b_off, b_mask, b_dcn, out);
}

// Round 7
// 192.762 us; speedup vs baseline: 1.1167x; 1.1167x over previous
//
#include <hip/hip_runtime.h>
#include <hip/hip_bf16.h>
#include <math.h>

#define Bt 8
#define Ct 64
#define Ht 128
#define Wt 128
#define Ot 64
#define HWt (Ht*Wt)

typedef __bf16 bf16x8 __attribute__((ext_vector_type(8)));
typedef float  f32x4  __attribute__((ext_vector_type(4)));

// fp32 -> bf16 bits, round-to-nearest-even, integer ops only
__device__ __forceinline__ uint f2bf_bits(float v) {
    uint u = __float_as_uint(v);
    uint lsb = (u >> 16) & 1u;
    return (u + 0x7fffu + lsb) >> 16;
}
__device__ __forceinline__ ushort f2bf(float v) {
    return (ushort)f2bf_bits(v);
}

// ---------------- prep ----------------
// blocks 0..1023: transpose x NCHW fp32 -> xTb NHWC bf16  [b][y][x][c]
// blocks 1024.. : weight reshapes
__global__ __launch_bounds__(256) void prep_kernel(
    const float* __restrict__ x, const float* __restrict__ w_off,
    const float* __restrict__ w_mask, const float* __restrict__ w_dcn,
    ushort* __restrict__ xTb, ushort* __restrict__ wOffB, ushort* __restrict__ wMainB)
{
    int blk = blockIdx.x;
    int t = threadIdx.x;
    if (blk < 1024) {
        __shared__ float L[64][128];
        int b = blk >> 7, y = blk & 127;
        const float* xb = x + (size_t)b * 1048576 + y * 128;
        // float4 loads: 2048 slots, 8 per thread, all independent
#pragma unroll
        for (int it = 0; it < 8; ++it) {
            int i = it * 256 + t;
            int c = i >> 5, x4 = i & 31;
            *(float4*)&L[c][x4 * 4] = *(const float4*)&xb[(size_t)c * HWt + x4 * 4];
        }
        __syncthreads();
        int px = t >> 1, half = (t & 1) * 32;
        union { ushort u[32]; uint4 q[4]; } pk;
#pragma unroll
        for (int i = 0; i < 32; ++i) pk.u[i] = f2bf(L[half + i][px]);
        uint4* dst = (uint4*)(xTb + ((size_t)blk * 128 + px) * 64 + half);
        dst[0] = pk.q[0]; dst[1] = pk.q[1]; dst[2] = pk.q[2]; dst[3] = pk.q[3];
    } else {
        int i = (blk - 1024) * 256 + t;
        if (i < 9 * 32 * 64) {
            int c = i & 63, ch = (i >> 6) & 31, k = i >> 11;
            float v = 0.f;
            if (ch < 18)      v = w_off[(ch * 64 + c) * 9 + k];
            else if (ch < 27) v = w_mask[((ch - 18) * 64 + c) * 9 + k];
            wOffB[i] = f2bf(v);
        } else {
            int j = i - 18432;
            if (j < 9 * 64 * 64) {
                int c = j & 63, o = (j >> 6) & 63, k = j >> 12;
                wMainB[j] = f2bf(w_dcn[(o * 64 + c) * 9 + k]);
            }
        }
    }
}

// ---------------- offset/mask conv via MFMA ----------------
// block: 512 thr, 128-px full row, 8 waves x M=16; N=32; K=576.
// wOffB staged once, unpadded + XOR-swizzled 16B groups (36.9 KB), 1 barrier.
__global__ __launch_bounds__(512) void offmask_kernel(
    const ushort* __restrict__ xTb, const ushort* __restrict__ wOffB,
    const float* __restrict__ b_off, const float* __restrict__ b_mask,
    float* __restrict__ dyp, float* __restrict__ dxp, float* __restrict__ mkp)
{
    __shared__ ushort wL[288 * 64];   // 36.9 KB, swizzled: group g of row r at col ((g+r)&7)*8

    int t = threadIdx.x;
    int p0 = blockIdx.x * 128;
    int b = p0 >> 14, y = (p0 >> 7) & 127;
    int wv = t >> 6, ln = t & 63;
    int m = ln & 15, cq = ln >> 4;
    int px = wv * 16 + m;

    // stage all 9 taps: 2304 16B-chunks
#pragma unroll
    for (int it = 0; it < 5; ++it) {
        int j = it * 512 + t;
        if (j < 2304) {
            int row = j >> 3, g = j & 7;
            int col = ((g + row) & 7) * 8;
            *(uint4*)&wL[row * 64 + col] = *(const uint4*)&wOffB[(size_t)row * 64 + g * 8];
        }
    }
    __syncthreads();

    f32x4 acc0 = {0.f, 0.f, 0.f, 0.f};
    f32x4 acc1 = {0.f, 0.f, 0.f, 0.f};
    const ushort* xbb = xTb + (size_t)b * 1048576;

#pragma unroll
    for (int k = 0; k < 9; ++k) {
        int ky = k / 3, kx = k - ky * 3;
        int yy = y + ky - 1;
        int xx = px + kx - 1;
        bool ok = ((unsigned)yy < 128u) && ((unsigned)xx < 128u);
        const ushort* arow = xbb + ((size_t)((yy << 7) + xx)) * 64;
        bf16x8 afr[2];
#pragma unroll
        for (int ks = 0; ks < 2; ++ks) {
            int c0 = ks * 32 + cq * 8;
            uint4 v = {0u, 0u, 0u, 0u};
            if (ok) v = *(const uint4*)&arow[c0];
            afr[ks] = __builtin_bit_cast(bf16x8, v);
        }
        int br0 = k * 32 + m;
        int br1 = k * 32 + 16 + m;
#pragma unroll
        for (int ks = 0; ks < 2; ++ks) {
            int gs = ks * 4 + cq;
            bf16x8 b0 = __builtin_bit_cast(bf16x8,
                *(const uint4*)&wL[br0 * 64 + ((gs + br0) & 7) * 8]);
            bf16x8 b1 = __builtin_bit_cast(bf16x8,
                *(const uint4*)&wL[br1 * 64 + ((gs + br1) & 7) * 8]);
            acc0 = __builtin_amdgcn_mfma_f32_16x16x32_bf16(afr[ks], b0, acc0, 0, 0, 0);
            acc1 = __builtin_amdgcn_mfma_f32_16x16x32_bf16(afr[ks], b1, acc1, 0, 0, 0);
        }
    }

    // epilogue: C layout col=lane&15 (ch), row=(lane>>4)*4+r (px)
    int n = m;
    int pxl = wv * 16 + (cq << 2);
#pragma unroll
    for (int r = 0; r < 4; ++r) {
        int pp = pxl + r;
        int sp = (y << 7) + pp;
        {
            float val = acc0[r] + b_off[n];
            float* dst = (n & 1) ? dxp : dyp;
            dst[((b * 9 + (n >> 1)) << 14) + sp] = val;
        }
        int ch = 16 + n;
        float v1 = acc1[r];
        if (ch < 18) {
            float val = v1 + b_off[ch];
            float* dst = (ch & 1) ? dxp : dyp;
            dst[((b * 9 + (ch >> 1)) << 14) + sp] = val;
        } else if (ch < 27) {
            float val = v1 + b_mask[ch - 18];
            mkp[((b * 9 + (ch - 18)) << 14) + sp] = 1.f / (1.f + __expf(-val));
        }
    }
}

// ---------------- main: bilinear sample + MFMA ----------------
// block: 512 thr, 128-px full row, 8 waves x M=16; N=64 (4 tiles); K=576.
// A fragments in registers; offsets preloaded to 27 regs; wS in 3-tap groups.
__global__ __launch_bounds__(512) void dcn_main_kernel(
    const ushort* __restrict__ xTb, const ushort* __restrict__ wMainB,
    const float* __restrict__ dyp, const float* __restrict__ dxp, const float* __restrict__ mkp,
    const float* __restrict__ b_dcn, float* __restrict__ out)
{
    __shared__ ushort wS[192 * 72];   // 27 KB, padded-72 rows (measured ~0-conflict)

    int t = threadIdx.x;
    int p0 = blockIdx.x * 128;
    int b = p0 >> 14, y = (p0 >> 7) & 127;
    int wv = t >> 6, ln = t & 63;
    int m = ln & 15, cq = ln >> 4;
    int px = wv * 16 + m;
    int sp = (y << 7) + px;

    // preload this lane's 27 offset/mask values (independent loads)
    float odm[3][9];
#pragma unroll
    for (int k = 0; k < 9; ++k) {
        odm[0][k] = dyp[((b * 9 + k) << 14) + sp];
        odm[1][k] = dxp[((b * 9 + k) << 14) + sp];
        odm[2][k] = mkp[((b * 9 + k) << 14) + sp];
    }

    f32x4 acc[4];
#pragma unroll
    for (int i = 0; i < 4; ++i) acc[i] = f32x4{0.f, 0.f, 0.f, 0.f};

    const ushort* xbb = xTb + (size_t)b * 1048576;
    float fx = (float)px;

#pragma unroll
    for (int g = 0; g < 3; ++g) {
        if (g > 0) __syncthreads();
        // stage taps 3g..3g+2: 1536 16B-chunks, 3 iters at 512 thr
#pragma unroll
        for (int it = 0; it < 3; ++it) {
            int j = it * 512 + t;
            int row = j >> 3, ch8 = j & 7;
            *(uint4*)&wS[row * 72 + ch8 * 8] =
                *(const uint4*)&wMainB[(size_t)(g * 192 + row) * 64 + ch8 * 8];
        }
        __syncthreads();

#pragma unroll
        for (int tl = 0; tl < 3; ++tl) {
            int k = g * 3 + tl;
            int ky = k / 3, kx = k - ky * 3;
            float dyv = odm[0][k];
            float dxv = odm[1][k];
            float mkv = odm[2][k];
            float py  = (float)(y + ky - 1) + dyv;
            float pxf = fx + (float)(kx - 1) + dxv;
            float y0f = floorf(py), x0f = floorf(pxf);
            float wy1 = py - y0f, wy0 = 1.f - wy1;
            float wx1 = pxf - x0f, wx0 = 1.f - wx1;
            bool vy0 = (y0f >= 0.f) && (y0f <= 127.f);
            bool vy1 = (y0f >= -1.f) && (y0f <= 126.f);
            bool vx0 = (x0f >= 0.f) && (x0f <= 127.f);
            bool vx1 = (x0f >= -1.f) && (x0f <= 126.f);
            float w00 = (vy0 && vx0) ? wy0 * wx0 * mkv : 0.f;
            float w01 = (vy0 && vx1) ? wy0 * wx1 * mkv : 0.f;
            float w10 = (vy1 && vx0) ? wy1 * wx0 * mkv : 0.f;
            float w11 = (vy1 && vx1) ? wy1 * wx1 * mkv : 0.f;
            int yi0 = (int)y0f, xi0 = (int)x0f;
            int y0c = min(max(yi0, 0), 127),     y1c = min(max(yi0 + 1, 0), 127);
            int x0c = min(max(xi0, 0), 127),     x1c = min(max(xi0 + 1, 0), 127);
            const ushort* p00 = xbb + (size_t)((y0c << 7) + x0c) * 64;
            const ushort* p01 = xbb + (size_t)((y0c << 7) + x1c) * 64;
            const ushort* p10 = xbb + (size_t)((y1c << 7) + x0c) * 64;
            const ushort* p11 = xbb + (size_t)((y1c << 7) + x1c) * 64;

            bf16x8 afr[2];
#pragma unroll
            for (int ks = 0; ks < 2; ++ks) {
                int c0 = ks * 32 + cq * 8;
                union { uint4 q; uint u[4]; } v00, v01, v10, v11, wr;
                v00.q = *(const uint4*)(p00 + c0);
                v01.q = *(const uint4*)(p01 + c0);
                v10.q = *(const uint4*)(p10 + c0);
                v11.q = *(const uint4*)(p11 + c0);
#pragma unroll
                for (int j = 0; j < 4; ++j) {
                    float f00l = __uint_as_float(v00.u[j] << 16);
                    float f00h = __uint_as_float(v00.u[j] & 0xffff0000u);
                    float f01l = __uint_as_float(v01.u[j] << 16);
                    float f01h = __uint_as_float(v01.u[j] & 0xffff0000u);
                    float f10l = __uint_as_float(v10.u[j] << 16);
                    float f10h = __uint_as_float(v10.u[j] & 0xffff0000u);
                    float f11l = __uint_as_float(v11.u[j] << 16);
                    float f11h = __uint_as_float(v11.u[j] & 0xffff0000u);
                    float vl = w00 * f00l;
                    vl = fmaf(w01, f01l, vl); vl = fmaf(w10, f10l, vl); vl = fmaf(w11, f11l, vl);
                    float vh = w00 * f00h;
                    vh = fmaf(w01, f01h, vh); vh = fmaf(w10, f10h, vh); vh = fmaf(w11, f11h, vh);
                    wr.u[j] = (f2bf_bits(vh) << 16) | f2bf_bits(vl);
                }
                afr[ks] = __builtin_bit_cast(bf16x8, wr.q);
            }

#pragma unroll
            for (int ks = 0; ks < 2; ++ks) {
                int c0 = ks * 32 + cq * 8;
#pragma unroll
                for (int nt = 0; nt < 4; ++nt) {
                    bf16x8 bb = __builtin_bit_cast(bf16x8,
                        *(const uint4*)&wS[(tl * 64 + nt * 16 + m) * 72 + c0]);
                    acc[nt] = __builtin_amdgcn_mfma_f32_16x16x32_bf16(afr[ks], bb, acc[nt], 0, 0, 0);
                }
            }
        }
    }

    // epilogue: direct coalesced float4 stores from C layout
#pragma unroll
    for (int nt = 0; nt < 4; ++nt) {
        int o = nt * 16 + m;
        float bias = b_dcn[o];
        float4 v;
        v.x = acc[nt][0] + bias;
        v.y = acc[nt][1] + bias;
        v.z = acc[nt][2] + bias;
        v.w = acc[nt][3] + bias;
        float* orow = out + ((size_t)(b * 64 + o) << 14) + (y << 7) + wv * 16 + cq * 4;
        *(float4*)orow = v;
    }
}

extern "C" void kernel_launch(void* const* d_in, const int* in_sizes, int n_in,
                              void* d_out, int out_size, void* d_ws, size_t ws_size,
                              hipStream_t stream) {
    const float* x      = (const float*)d_in[0];
    const float* w_off  = (const float*)d_in[1];
    const float* b_off  = (const float*)d_in[2];
    const float* w_mask = (const float*)d_in[3];
    const float* b_mask = (const float*)d_in[4];
    const float* w_dcn  = (const float*)d_in[5];
    const float* b_dcn  = (const float*)d_in[6];
    float* out = (float*)d_out;

    const size_t N1 = (size_t)Bt * 9 * HWt;          // 1179648 floats
    float* ws  = (float*)d_ws;
    float* dyp = ws;
    float* dxp = ws + N1;
    float* mkp = ws + 2 * N1;
    ushort* xTb   = (ushort*)(ws + 3 * N1);          // 8.4M bf16
    ushort* wOffB = xTb + (size_t)Bt * HWt * 64;     // 18432
    ushort* wMainB = wOffB + 18432;                  // 36864

    hipLaunchKernelGGL(prep_kernel, dim3(1024 + 216), dim3(256), 0, stream,
                       x, w_off, w_mask, w_dcn, xTb, wOffB, wMainB);
    hipLaunchKernelGGL(offmask_kernel, dim3(1024), dim3(512), 0, stream,
                       xTb, wOffB, b_off, b_mask, dyp, dxp, mkp);
    hipLaunchKernelGGL(dcn_main_kernel, dim3(1024), dim3(512), 0, stream,
                       xTb, wMainB, dyp, dxp, mkp, b_dcn, out);
}